// Round 3
// baseline (472.689 us; speedup 1.0000x reference)
//
#include <hip/hip_runtime.h>
#include <math.h>

#define HH 512
#define WW 512
#define BB 32
#define KK 8
#define SPLIT 8
#define NBLK (BB * KK * SPLIT)      // 2048 blocks
#define CHUNK ((HH * WW) / SPLIT)   // 32768 floats per block
#define BLOCK 256

// Fused: per-block partial argmax over one (b,k) segment, then the LAST block
// to finish (device-scope atomic counter) performs the finalize reduction.
// ws layout: [0..3] counter (zeroed via hipMemsetAsync), pval @ +256 B (2048 f32),
// pidx @ +256+8192 B (2048 i32).
__global__ __launch_bounds__(BLOCK) void keypoint_loss_fused(
    const float* __restrict__ hm, const float* __restrict__ gt,
    const float* __restrict__ m0, const float* __restrict__ m1,
    const float* __restrict__ m2,
    unsigned int* __restrict__ counter,
    float* __restrict__ pval, int* __restrict__ pidx,
    float* __restrict__ out)
{
    const int blk = blockIdx.x;
    const int seg = blk % SPLIT;
    const int bk  = blk / SPLIT;
    const int t   = threadIdx.x;

    const float4* base =
        reinterpret_cast<const float4*>(hm + (size_t)bk * (HH * WW) + (size_t)seg * CHUNK);

    float bv = -INFINITY;
    int   bi = 0x7fffffff;

    const int n4 = CHUNK / 4;  // 8192 float4 per block
    // per-thread flat-index sequence is strictly increasing, so strict '>' keeps
    // the first occurrence (jnp.argmax tie semantics within a thread)
    for (int i = t; i < n4; i += BLOCK) {
        float4 v = base[i];
        int i0 = seg * CHUNK + i * 4;
        if (v.x > bv) { bv = v.x; bi = i0;     }
        if (v.y > bv) { bv = v.y; bi = i0 + 1; }
        if (v.z > bv) { bv = v.z; bi = i0 + 2; }
        if (v.w > bv) { bv = v.w; bi = i0 + 3; }
    }

    __shared__ float sv[BLOCK];
    __shared__ int   si[BLOCK];
    sv[t] = bv; si[t] = bi;
    __syncthreads();
    for (int s = BLOCK / 2; s > 0; s >>= 1) {
        if (t < s) {
            float ov = sv[t + s]; int oi = si[t + s];
            // tie-break: lower flat index wins (first occurrence)
            if (ov > sv[t] || (ov == sv[t] && oi < si[t])) { sv[t] = ov; si[t] = oi; }
        }
        __syncthreads();
    }

    __shared__ bool is_last;
    if (t == 0) {
        pval[blk] = sv[0];
        pidx[blk] = si[0];
        __threadfence();                               // release: partials visible device-wide
        unsigned int done = atomicAdd(counter, 1u);    // device-scope by default on CDNA
        is_last = (done == NBLK - 1);
    }
    __syncthreads();
    if (!is_last) return;
    __threadfence();                                   // acquire: see all blocks' partials

    // ---- finalize (only the last block, 256 threads; thread t = pair b*K+k) ----
    const int b = t / KK;

    float fv = -INFINITY;
    int   fi = 0x7fffffff;
    for (int s = 0; s < SPLIT; ++s) {
        float v = pval[t * SPLIT + s];
        int   i = pidx[t * SPLIT + s];
        if (v > fv || (v == fv && i < fi)) { fv = v; fi = i; }
    }

    const float x = (float)(fi % WW) * (1.0f / (WW - 1));
    const float y = (float)(fi / WW) * (1.0f / (HH - 1));

    // reference: ix = floor(clip(x,0,511)) in {0,1}; same for y
    const int ix = (int)floorf(fminf(fmaxf(x, 0.0f), 511.0f));
    const int iy = (int)floorf(fminf(fmaxf(y, 0.0f), 511.0f));
    const float fx = fabsf(x - (float)ix);
    const float fy = fabsf(y - (float)iy);

    // reference gathers padding_mask[b, ix, iy] (x-coord indexes dim-1)
    const size_t mo = (size_t)b * (HH * WW) + (size_t)ix * WW + (size_t)iy;
    const float g0 = m0[mo];
    const float g1 = m1[mo];
    const float g2 = m2[mo];

    const float gtx = gt[t * 2 + 0];
    const float gty = gt[t * 2 + 1];

    // |x-gtx|+|y-gty| + 3*10*(fx+fy) + 10*10*((1-g0)+(1-g1)+(1-g2))
    float loss = fabsf(x - gtx) + fabsf(y - gty)
               + 30.0f  * (fx + fy)
               + 100.0f * (3.0f - g0 - g1 - g2);

    __shared__ float ss[BLOCK];
    ss[t] = loss;
    __syncthreads();
    for (int s = BLOCK / 2; s > 0; s >>= 1) {
        if (t < s) ss[t] += ss[t + s];
        __syncthreads();
    }
    if (t == 0) out[0] = ss[0];
}

extern "C" void kernel_launch(void* const* d_in, const int* in_sizes, int n_in,
                              void* d_out, int out_size, void* d_ws, size_t ws_size,
                              hipStream_t stream)
{
    const float* hm = (const float*)d_in[0];   // (32, 8, 512, 512) f32
    const float* gt = (const float*)d_in[1];   // (32, 8, 2) f32
    const float* m0 = (const float*)d_in[2];   // (32, 512, 512) f32
    const float* m1 = (const float*)d_in[3];
    const float* m2 = (const float*)d_in[4];

    unsigned int* counter = (unsigned int*)d_ws;
    float* pval = (float*)((char*)d_ws + 256);
    int*   pidx = (int*)((char*)d_ws + 256 + NBLK * sizeof(float));

    // zero the completion counter (graph-capture-legal async memset)
    hipMemsetAsync(d_ws, 0, 4, stream);

    keypoint_loss_fused<<<NBLK, BLOCK, 0, stream>>>(
        hm, gt, m0, m1, m2, counter, pval, pidx, (float*)d_out);
}

// Round 4
// 402.357 us; speedup vs baseline: 1.1748x; 1.1748x over previous
//
#include <hip/hip_runtime.h>
#include <math.h>

#define HH 512
#define WW 512
#define BB 32
#define KK 8
#define SPLIT 8
#define NBLK (BB * KK * SPLIT)      // 2048 blocks
#define CHUNK ((HH * WW) / SPLIT)   // 32768 floats per block
#define BLOCK 256
#define MLP 8                        // independent load chains per thread

// Kernel 1: partial argmax per (b,k) segment, 8-way unrolled for memory-level
// parallelism: 8 independent float4 loads + 8 independent accumulator chains
// per thread -> 8KB in flight per wave (vs 1KB serial), hiding HBM latency.
__global__ __launch_bounds__(BLOCK) void argmax_partial(
    const float* __restrict__ hm, float* __restrict__ pval, int* __restrict__ pidx)
{
    const int blk = blockIdx.x;
    const int seg = blk % SPLIT;
    const int bk  = blk / SPLIT;
    const int t   = threadIdx.x;

    const float4* base =
        reinterpret_cast<const float4*>(hm + (size_t)bk * (HH * WW) + (size_t)seg * CHUNK);

    float bv[MLP];
    int   bi[MLP];
#pragma unroll
    for (int j = 0; j < MLP; ++j) { bv[j] = -INFINITY; bi[j] = 0x7fffffff; }

    const int n4 = CHUNK / 4;  // 8192 float4 per block
    // outer loop: 4 iterations; each issues 8 independent dwordx4 loads
    for (int b0 = 0; b0 < n4; b0 += MLP * BLOCK) {
        float4 v[MLP];
        int    ii[MLP];
#pragma unroll
        for (int j = 0; j < MLP; ++j) {
            ii[j] = b0 + j * BLOCK + t;
            v[j]  = base[ii[j]];
        }
#pragma unroll
        for (int j = 0; j < MLP; ++j) {
            const int i0 = seg * CHUNK + ii[j] * 4;
            // per-chain index sequence strictly increasing -> strict '>' keeps
            // first occurrence within the chain
            if (v[j].x > bv[j]) { bv[j] = v[j].x; bi[j] = i0;     }
            if (v[j].y > bv[j]) { bv[j] = v[j].y; bi[j] = i0 + 1; }
            if (v[j].z > bv[j]) { bv[j] = v[j].z; bi[j] = i0 + 2; }
            if (v[j].w > bv[j]) { bv[j] = v[j].w; bi[j] = i0 + 3; }
        }
    }

    // merge the 8 chains: strictly-greater wins; equal value -> lowest index.
    // This is exactly first-occurrence argmax over the union of chains.
    float mv = bv[0]; int mi = bi[0];
#pragma unroll
    for (int j = 1; j < MLP; ++j) {
        if (bv[j] > mv || (bv[j] == mv && bi[j] < mi)) { mv = bv[j]; mi = bi[j]; }
    }

    __shared__ float sv[BLOCK];
    __shared__ int   si[BLOCK];
    sv[t] = mv; si[t] = mi;
    __syncthreads();
    for (int s = BLOCK / 2; s > 0; s >>= 1) {
        if (t < s) {
            float ov = sv[t + s]; int oi = si[t + s];
            if (ov > sv[t] || (ov == sv[t] && oi < si[t])) { sv[t] = ov; si[t] = oi; }
        }
        __syncthreads();
    }
    if (t == 0) { pval[blk] = sv[0]; pidx[blk] = si[0]; }
}

// Kernel 2: one block, 256 threads; thread t = (b,k) pair.
__global__ __launch_bounds__(BLOCK) void finalize(
    const float* __restrict__ pval, const int* __restrict__ pidx,
    const float* __restrict__ gt,
    const float* __restrict__ m0, const float* __restrict__ m1,
    const float* __restrict__ m2, float* __restrict__ out)
{
    const int t = threadIdx.x;        // t = b*K + k
    const int b = t / KK;

    float fv = -INFINITY;
    int   fi = 0x7fffffff;
    for (int s = 0; s < SPLIT; ++s) {
        float v = pval[t * SPLIT + s];
        int   i = pidx[t * SPLIT + s];
        if (v > fv || (v == fv && i < fi)) { fv = v; fi = i; }
    }

    const float x = (float)(fi % WW) * (1.0f / (WW - 1));
    const float y = (float)(fi / WW) * (1.0f / (HH - 1));

    // reference: ix = floor(clip(x,0,511)) in {0,1}; same for y
    const int ix = (int)floorf(fminf(fmaxf(x, 0.0f), 511.0f));
    const int iy = (int)floorf(fminf(fmaxf(y, 0.0f), 511.0f));
    const float fx = fabsf(x - (float)ix);
    const float fy = fabsf(y - (float)iy);

    // reference gathers padding_mask[b, ix, iy] (x-coord indexes dim-1)
    const size_t mo = (size_t)b * (HH * WW) + (size_t)ix * WW + (size_t)iy;
    const float g0 = m0[mo];
    const float g1 = m1[mo];
    const float g2 = m2[mo];

    const float gtx = gt[t * 2 + 0];
    const float gty = gt[t * 2 + 1];

    // |x-gtx|+|y-gty| + 3*10*(fx+fy) + 10*10*((1-g0)+(1-g1)+(1-g2))
    float loss = fabsf(x - gtx) + fabsf(y - gty)
               + 30.0f  * (fx + fy)
               + 100.0f * (3.0f - g0 - g1 - g2);

    __shared__ float ss[BLOCK];
    ss[t] = loss;
    __syncthreads();
    for (int s = BLOCK / 2; s > 0; s >>= 1) {
        if (t < s) ss[t] += ss[t + s];
        __syncthreads();
    }
    if (t == 0) out[0] = ss[0];
}

extern "C" void kernel_launch(void* const* d_in, const int* in_sizes, int n_in,
                              void* d_out, int out_size, void* d_ws, size_t ws_size,
                              hipStream_t stream)
{
    const float* hm = (const float*)d_in[0];   // (32, 8, 512, 512) f32
    const float* gt = (const float*)d_in[1];   // (32, 8, 2) f32
    const float* m0 = (const float*)d_in[2];   // (32, 512, 512) f32
    const float* m1 = (const float*)d_in[3];
    const float* m2 = (const float*)d_in[4];

    float* pval = (float*)d_ws;                              // 2048 floats
    int*   pidx = (int*)((char*)d_ws + NBLK * sizeof(float));

    argmax_partial<<<NBLK, BLOCK, 0, stream>>>(hm, pval, pidx);
    finalize<<<1, BLOCK, 0, stream>>>(pval, pidx, gt, m0, m1, m2, (float*)d_out);
}

// Round 5
// 399.559 us; speedup vs baseline: 1.1830x; 1.0070x over previous
//
#include <hip/hip_runtime.h>
#include <math.h>

#define HH 512
#define WW 512
#define BB 32
#define KK 8
#define SPLIT 8
#define NBLK (BB * KK * SPLIT)      // 2048 blocks
#define CHUNK ((HH * WW) / SPLIT)   // 32768 floats per block
#define BLOCK 256
#define MLP 8                        // independent chains

// Kernel 1: per-(b,k)-segment argmax, two-pass:
//   pass1: pure value-max, 8 independent fmax chains -> loads have NO index
//          dependency web, full memory-level parallelism.
//   pass2: re-scan same data (L2/L3-hot, block-local reuse) for min index
//          equal to the thread max (branchless; ascending order = first occurrence).
__global__ __launch_bounds__(BLOCK) void argmax_partial(
    const float* __restrict__ hm, float* __restrict__ pval, int* __restrict__ pidx)
{
    const int blk = blockIdx.x;
    const int seg = blk % SPLIT;
    const int bk  = blk / SPLIT;
    const int t   = threadIdx.x;

    const float4* base =
        reinterpret_cast<const float4*>(hm + (size_t)bk * (HH * WW) + (size_t)seg * CHUNK);

    const int n4 = CHUNK / 4;  // 8192 float4 per block; 32 per thread

    // ---- pass 1: value max only ----
    float m[MLP];
#pragma unroll
    for (int j = 0; j < MLP; ++j) m[j] = -INFINITY;

    for (int b0 = 0; b0 < n4; b0 += MLP * BLOCK) {
        float4 v[MLP];
#pragma unroll
        for (int j = 0; j < MLP; ++j) v[j] = base[b0 + j * BLOCK + t];
#pragma unroll
        for (int j = 0; j < MLP; ++j) {
            m[j] = fmaxf(m[j], fmaxf(fmaxf(v[j].x, v[j].y), fmaxf(v[j].z, v[j].w)));
        }
    }
    float tmax = m[0];
#pragma unroll
    for (int j = 1; j < MLP; ++j) tmax = fmaxf(tmax, m[j]);

    // ---- pass 2: min flat index equal to tmax (first occurrence) ----
    int bi[MLP];
#pragma unroll
    for (int j = 0; j < MLP; ++j) bi[j] = 0x7fffffff;

    for (int b0 = 0; b0 < n4; b0 += MLP * BLOCK) {
        float4 v[MLP];
#pragma unroll
        for (int j = 0; j < MLP; ++j) v[j] = base[b0 + j * BLOCK + t];
#pragma unroll
        for (int j = 0; j < MLP; ++j) {
            const int i0 = seg * CHUNK + (b0 + j * BLOCK + t) * 4;
            if (v[j].x == tmax && i0     < bi[j]) bi[j] = i0;
            if (v[j].y == tmax && i0 + 1 < bi[j]) bi[j] = i0 + 1;
            if (v[j].z == tmax && i0 + 2 < bi[j]) bi[j] = i0 + 2;
            if (v[j].w == tmax && i0 + 3 < bi[j]) bi[j] = i0 + 3;
        }
    }
    int ti = bi[0];
#pragma unroll
    for (int j = 1; j < MLP; ++j) ti = min(ti, bi[j]);
    // ti is min index among elements equal to tmax (INT_MAX if thread has none...
    // impossible: tmax came from this thread's own elements)

    // ---- block reduce (val desc, idx asc tie-break) ----
    __shared__ float sv[BLOCK];
    __shared__ int   si[BLOCK];
    sv[t] = tmax; si[t] = ti;
    __syncthreads();
    for (int s = BLOCK / 2; s > 0; s >>= 1) {
        if (t < s) {
            float ov = sv[t + s]; int oi = si[t + s];
            if (ov > sv[t] || (ov == sv[t] && oi < si[t])) { sv[t] = ov; si[t] = oi; }
        }
        __syncthreads();
    }
    if (t == 0) { pval[blk] = sv[0]; pidx[blk] = si[0]; }
}

// Kernel 2: one block, 256 threads; thread t = (b,k) pair.
__global__ __launch_bounds__(BLOCK) void finalize(
    const float* __restrict__ pval, const int* __restrict__ pidx,
    const float* __restrict__ gt,
    const float* __restrict__ m0, const float* __restrict__ m1,
    const float* __restrict__ m2, float* __restrict__ out)
{
    const int t = threadIdx.x;        // t = b*K + k
    const int b = t / KK;

    float fv = -INFINITY;
    int   fi = 0x7fffffff;
    for (int s = 0; s < SPLIT; ++s) {
        float v = pval[t * SPLIT + s];
        int   i = pidx[t * SPLIT + s];
        if (v > fv || (v == fv && i < fi)) { fv = v; fi = i; }
    }

    const float x = (float)(fi % WW) * (1.0f / (WW - 1));
    const float y = (float)(fi / WW) * (1.0f / (HH - 1));

    // reference: ix = floor(clip(x,0,511)) in {0,1}; same for y
    const int ix = (int)floorf(fminf(fmaxf(x, 0.0f), 511.0f));
    const int iy = (int)floorf(fminf(fmaxf(y, 0.0f), 511.0f));
    const float fx = fabsf(x - (float)ix);
    const float fy = fabsf(y - (float)iy);

    // reference gathers padding_mask[b, ix, iy] (x-coord indexes dim-1)
    const size_t mo = (size_t)b * (HH * WW) + (size_t)ix * WW + (size_t)iy;
    const float g0 = m0[mo];
    const float g1 = m1[mo];
    const float g2 = m2[mo];

    const float gtx = gt[t * 2 + 0];
    const float gty = gt[t * 2 + 1];

    // |x-gtx|+|y-gty| + 3*10*(fx+fy) + 10*10*((1-g0)+(1-g1)+(1-g2))
    float loss = fabsf(x - gtx) + fabsf(y - gty)
               + 30.0f  * (fx + fy)
               + 100.0f * (3.0f - g0 - g1 - g2);

    __shared__ float ss[BLOCK];
    ss[t] = loss;
    __syncthreads();
    for (int s = BLOCK / 2; s > 0; s >>= 1) {
        if (t < s) ss[t] += ss[t + s];
        __syncthreads();
    }
    if (t == 0) out[0] = ss[0];
}

extern "C" void kernel_launch(void* const* d_in, const int* in_sizes, int n_in,
                              void* d_out, int out_size, void* d_ws, size_t ws_size,
                              hipStream_t stream)
{
    const float* hm = (const float*)d_in[0];   // (32, 8, 512, 512) f32
    const float* gt = (const float*)d_in[1];   // (32, 8, 2) f32
    const float* m0 = (const float*)d_in[2];   // (32, 512, 512) f32
    const float* m1 = (const float*)d_in[3];
    const float* m2 = (const float*)d_in[4];

    float* pval = (float*)d_ws;                              // 2048 floats
    int*   pidx = (int*)((char*)d_ws + NBLK * sizeof(float));

    argmax_partial<<<NBLK, BLOCK, 0, stream>>>(hm, pval, pidx);
    finalize<<<1, BLOCK, 0, stream>>>(pval, pidx, gt, m0, m1, m2, (float*)d_out);
}

// Round 9
// 375.430 us; speedup vs baseline: 1.2591x; 1.0643x over previous
//
#include <hip/hip_runtime.h>
#include <math.h>

#define HH 512
#define WW 512
#define BB 32
#define KK 8
#define SPLIT 8
#define NBLK (BB * KK * SPLIT)      // 2048 blocks
#define CHUNK ((HH * WW) / SPLIT)   // 32768 floats per block
#define BLOCK 256
#define MLP 4                        // independent load+max chains per thread

typedef unsigned long long u64;
typedef unsigned int u32;
typedef float f4 __attribute__((ext_vector_type(4)));   // builtin-compatible float4

// Monotone float->u32 key: a > b  <=>  fkey(a) > fkey(b)  (all finite floats, +-inf)
__device__ __forceinline__ u32 fkey(float f) {
    u32 b = __float_as_uint(f);
    u32 m = (u32)((int)b >> 31);        // all-ones if negative
    return b ^ (m | 0x80000000u);
}

// Kernel 1: per-(b,k)-segment argmax via ASSOCIATIVE packed-u64 max:
// packed = (key << 32) | ~idx. max() tree-reduces (no conditional-update
// dependency web); ties pick larger ~idx = smaller idx = first occurrence.
__global__ __launch_bounds__(BLOCK) void argmax_partial(
    const float* __restrict__ hm, u64* __restrict__ pbest)
{
    const int blk = blockIdx.x;
    const int seg = blk % SPLIT;
    const int bk  = blk / SPLIT;
    const int t   = threadIdx.x;

    const f4* base =
        reinterpret_cast<const f4*>(hm + (size_t)bk * (HH * WW) + (size_t)seg * CHUNK);

    const int n4 = CHUNK / 4;  // 8192 float4 per block; 32 per thread

    u64 best[MLP];
#pragma unroll
    for (int j = 0; j < MLP; ++j) best[j] = 0ull;

    for (int b0 = 0; b0 < n4; b0 += MLP * BLOCK) {
        f4 v[MLP];
#pragma unroll
        for (int j = 0; j < MLP; ++j)
            v[j] = __builtin_nontemporal_load(&base[b0 + j * BLOCK + t]);
#pragma unroll
        for (int j = 0; j < MLP; ++j) {
            const u32 i0 = (u32)(seg * CHUNK + (b0 + j * BLOCK + t) * 4);
            u64 p0 = ((u64)fkey(v[j].x) << 32) | (u32)~(i0);
            u64 p1 = ((u64)fkey(v[j].y) << 32) | (u32)~(i0 + 1);
            u64 p2 = ((u64)fkey(v[j].z) << 32) | (u32)~(i0 + 2);
            u64 p3 = ((u64)fkey(v[j].w) << 32) | (u32)~(i0 + 3);
            u64 q0 = p0 > p1 ? p0 : p1;
            u64 q1 = p2 > p3 ? p2 : p3;
            u64 q  = q0 > q1 ? q0 : q1;
            best[j] = q > best[j] ? q : best[j];
        }
    }
    u64 tb = best[0];
#pragma unroll
    for (int j = 1; j < MLP; ++j) tb = best[j] > tb ? best[j] : tb;

    __shared__ u64 sb[BLOCK];
    sb[t] = tb;
    __syncthreads();
    for (int s = BLOCK / 2; s > 0; s >>= 1) {
        if (t < s) { u64 o = sb[t + s]; if (o > sb[t]) sb[t] = o; }
        __syncthreads();
    }
    if (t == 0) pbest[blk] = sb[0];
}

// Kernel 2: one block, 256 threads; thread t = (b,k) pair.
__global__ __launch_bounds__(BLOCK) void finalize(
    const u64* __restrict__ pbest,
    const float* __restrict__ gt,
    const float* __restrict__ m0, const float* __restrict__ m1,
    const float* __restrict__ m2, float* __restrict__ out)
{
    const int t = threadIdx.x;        // t = b*K + k
    const int b = t / KK;

    u64 best = 0ull;
    for (int s = 0; s < SPLIT; ++s) {
        u64 p = pbest[t * SPLIT + s];
        if (p > best) best = p;       // packed max: ties -> smaller idx
    }
    const int fi = (int)(~(u32)(best & 0xFFFFFFFFu));   // flat argmax index

    const float x = (float)(fi % WW) * (1.0f / (WW - 1));
    const float y = (float)(fi / WW) * (1.0f / (HH - 1));

    // reference: ix = floor(clip(x,0,511)) in {0,1}; same for y
    const int ix = (int)floorf(fminf(fmaxf(x, 0.0f), 511.0f));
    const int iy = (int)floorf(fminf(fmaxf(y, 0.0f), 511.0f));
    const float fx = fabsf(x - (float)ix);
    const float fy = fabsf(y - (float)iy);

    // reference gathers padding_mask[b, ix, iy] (x-coord indexes dim-1)
    const size_t mo = (size_t)b * (HH * WW) + (size_t)ix * WW + (size_t)iy;
    const float g0 = m0[mo];
    const float g1 = m1[mo];
    const float g2 = m2[mo];

    const float gtx = gt[t * 2 + 0];
    const float gty = gt[t * 2 + 1];

    // |x-gtx|+|y-gty| + 3*10*(fx+fy) + 10*10*((1-g0)+(1-g1)+(1-g2))
    float loss = fabsf(x - gtx) + fabsf(y - gty)
               + 30.0f  * (fx + fy)
               + 100.0f * (3.0f - g0 - g1 - g2);

    __shared__ float ss[BLOCK];
    ss[t] = loss;
    __syncthreads();
    for (int s = BLOCK / 2; s > 0; s >>= 1) {
        if (t < s) ss[t] += ss[t + s];
        __syncthreads();
    }
    if (t == 0) out[0] = ss[0];
}

extern "C" void kernel_launch(void* const* d_in, const int* in_sizes, int n_in,
                              void* d_out, int out_size, void* d_ws, size_t ws_size,
                              hipStream_t stream)
{
    const float* hm = (const float*)d_in[0];   // (32, 8, 512, 512) f32
    const float* gt = (const float*)d_in[1];   // (32, 8, 2) f32
    const float* m0 = (const float*)d_in[2];   // (32, 512, 512) f32
    const float* m1 = (const float*)d_in[3];
    const float* m2 = (const float*)d_in[4];

    u64* pbest = (u64*)d_ws;                   // 2048 * 8 B = 16 KB

    argmax_partial<<<NBLK, BLOCK, 0, stream>>>(hm, pbest);
    finalize<<<1, BLOCK, 0, stream>>>(pbest, gt, m0, m1, m2, (float*)d_out);
}